// Round 1
// 4237.273 us; speedup vs baseline: 1.5259x; 1.5259x over previous
//
#include <hip/hip_runtime.h>
#include <math.h>

// ---------------- common types ----------------
typedef __attribute__((ext_vector_type(8))) short bf16x8;
typedef __attribute__((ext_vector_type(4))) float f32x4;

__device__ __forceinline__ unsigned short f2bf(float x) {
    unsigned u = __float_as_uint(x);
    unsigned r = (u + 0x7FFF + ((u >> 16) & 1)) >> 16;
    return (unsigned short)r;
}
__device__ __forceinline__ float bf_lo(unsigned u) { return __uint_as_float(u << 16); }
__device__ __forceinline__ float bf_hi(unsigned u) { return __uint_as_float(u & 0xffff0000u); }

#define ACT_NONE  0
#define ACT_RELU  1
#define ACT_RELU2 2

// ---------------- MFMA GEMM: C[M,N] = act(A[M,K] @ B[N,K]^T + bias[N]) ----------------
// 64x64 tile, BK=32, 256 threads (4 waves, each 32x32 via 2x2 of 16x16x32 mfma).
template <int ACT, bool GATHER, bool TRANSOUT>
__global__ __launch_bounds__(256) void gemm_bt(
    const float* __restrict__ A, const float* __restrict__ Bm,
    const float* __restrict__ bias, float* __restrict__ C,
    const int* __restrict__ ids, int M, int N, int K)
{
    __shared__ unsigned short as_[64][40];
    __shared__ unsigned short bs_[64][40];

    const int tid = threadIdx.x;
    const int bm = blockIdx.x, bn = blockIdx.y;
    const int r = tid >> 2, seg = tid & 3;

    const int arow = bm * 64 + r;
    const float* aptr = GATHER ? (A + (size_t)ids[arow] * K) : (A + (size_t)arow * K);
    const float* bptr = Bm + (size_t)(bn * 64 + r) * K;

    const int w = tid >> 6, lane = tid & 63;
    const int wr = w >> 1, wc = w & 1;
    const int al = lane & 15, kq = lane >> 4;

    f32x4 acc[2][2];
    for (int mi = 0; mi < 2; ++mi)
        for (int ni = 0; ni < 2; ++ni)
            acc[mi][ni] = (f32x4){0.f, 0.f, 0.f, 0.f};

    for (int k0 = 0; k0 < K; k0 += 32) {
        __syncthreads();
        {
            const float4* ap4 = (const float4*)(aptr + k0 + seg * 8);
            float4 a0 = ap4[0], a1 = ap4[1];
            uint4 pk;
            pk.x = (unsigned)f2bf(a0.x) | ((unsigned)f2bf(a0.y) << 16);
            pk.y = (unsigned)f2bf(a0.z) | ((unsigned)f2bf(a0.w) << 16);
            pk.z = (unsigned)f2bf(a1.x) | ((unsigned)f2bf(a1.y) << 16);
            pk.w = (unsigned)f2bf(a1.z) | ((unsigned)f2bf(a1.w) << 16);
            *(uint4*)&as_[r][seg * 8] = pk;

            const float4* bp4 = (const float4*)(bptr + k0 + seg * 8);
            float4 b0 = bp4[0], b1 = bp4[1];
            pk.x = (unsigned)f2bf(b0.x) | ((unsigned)f2bf(b0.y) << 16);
            pk.y = (unsigned)f2bf(b0.z) | ((unsigned)f2bf(b0.w) << 16);
            pk.z = (unsigned)f2bf(b1.x) | ((unsigned)f2bf(b1.y) << 16);
            pk.w = (unsigned)f2bf(b1.z) | ((unsigned)f2bf(b1.w) << 16);
            *(uint4*)&bs_[r][seg * 8] = pk;
        }
        __syncthreads();

        bf16x8 af[2], bfr[2];
        af[0]  = *(const bf16x8*)&as_[wr * 32 + al][kq * 8];
        af[1]  = *(const bf16x8*)&as_[wr * 32 + 16 + al][kq * 8];
        bfr[0] = *(const bf16x8*)&bs_[wc * 32 + al][kq * 8];
        bfr[1] = *(const bf16x8*)&bs_[wc * 32 + 16 + al][kq * 8];

        for (int mi = 0; mi < 2; ++mi)
            for (int ni = 0; ni < 2; ++ni)
                acc[mi][ni] = __builtin_amdgcn_mfma_f32_16x16x32_bf16(
                    af[mi], bfr[ni], acc[mi][ni], 0, 0, 0);
    }

    for (int mi = 0; mi < 2; ++mi) {
        for (int ni = 0; ni < 2; ++ni) {
            const int gcol = bn * 64 + wc * 32 + ni * 16 + al;
            const float bv = bias ? bias[gcol] : 0.f;
            for (int i = 0; i < 4; ++i) {
                const int grow = bm * 64 + wr * 32 + mi * 16 + kq * 4 + i;
                float v = acc[mi][ni][i] + bv;
                if (ACT == ACT_RELU)  v = fmaxf(v, 0.f);
                if (ACT == ACT_RELU2) { v = fmaxf(v, 0.f); v = v * v; }
                if (TRANSOUT) {
                    const int b = grow >> 10, s = grow & 1023;
                    C[((size_t)b * N + gcol) * 1024 + s] = v;
                } else {
                    C[(size_t)grow * N + gcol] = v;
                }
            }
        }
    }
}

// ---------------- workspace init ----------------
__global__ void init_ws(float* hbuf, int* flags) {
    int t = blockIdx.x * 256 + threadIdx.x;
    if (t < 4096) hbuf[t] = 0.f;
    if (t < 128 * 32) flags[t] = 0;
}

// ---------------- GRU persistent kernel ----------------
// 128 WGs x 256 threads, co-resident. WG wg owns hidden units u0=wg*8 .. u0+7.
// Redesigned communication:
//  - h loaded DIRECTLY from MALL into registers (8x global_load_dwordx4 sc0 sc1,
//    one latency), no LDS mirror.
//  - barrier = padded per-WG flag array: publish (store + vmcnt) then plain
//    agent-scope flag store; wave 0 of each WG polls all 128 flags in parallel.
//    No serialized atomic chain, no s_sleep quantization.
//  - xp gate inputs (ir/iz/inn) prefetched at loop top (independent of h).
//  - hprev kept in a register (it is this WG's own value from last step).
__global__ __launch_bounds__(256, 1) void gru_kernel(
    const float* __restrict__ xp,     // [2048][3072], row = b*1024+t (b_ih added)
    const float* __restrict__ w_hh,   // [3072][1024]
    const float* __restrict__ b_hh,   // [3072]
    float* __restrict__ states,       // [2048][1024]
    float* __restrict__ hbuf,         // 2 x [2][1024] (buf0 zero-initialized)
    int* __restrict__ flags)          // 128 flags, padded stride 32 ints
{
    __shared__ unsigned short wlds[24 * 1024];  // bf16 weights
    __shared__ float ghs[24][2];
    __shared__ float bh[24];

    const int wg = blockIdx.x, tid = threadIdx.x;
    const int u0 = wg * 8;

    for (int idx = tid; idx < 24 * 1024; idx += 256) {
        const int rr = idx >> 10, kk = idx & 1023;
        const int grow = (rr < 8) ? (u0 + rr) : (rr < 16) ? (1024 + u0 + rr - 8) : (2048 + u0 + rr - 16);
        wlds[idx] = f2bf(w_hh[((size_t)grow << 10) | kk]);
    }
    if (tid < 24) {
        const int rr = tid;
        const int grow = (rr < 8) ? (u0 + rr) : (rr < 16) ? (1024 + u0 + rr - 8) : (2048 + u0 + rr - 16);
        bh[rr] = b_hh[grow];
    }
    __syncthreads();

    const int w = tid >> 6, lane = tid & 63;
    const int j = tid & 7, bb = (tid >> 3) & 1;          // pointwise mapping (tid<16)
    const float* xbase = xp + ((size_t)(bb << 10)) * 3072 + u0 + j;
    float hprev = 0.f;

    for (int t = 0; t < 1024; ++t) {
        const int p = t & 1;
        const float* src = hbuf + p * 2048;
        float* dst = hbuf + (1 - p) * 2048;

        // ---- prefetch xp gates (independent of h) ----
        float ir = 0.f, iz = 0.f, inn = 0.f;
        if (tid < 16) {
            const float* xr = xbase + (size_t)t * 3072;
            ir = xr[0]; iz = xr[1024]; inn = xr[2048];
        }

        // ---- wave 0: poll all 128 flags (parallel, 2 loads/lane) ----
        if (w == 0 && t > 0) {
            const int need = t;
            for (;;) {
                int f0 = __hip_atomic_load(&flags[lane << 5],
                                           __ATOMIC_RELAXED, __HIP_MEMORY_SCOPE_AGENT);
                int f1 = __hip_atomic_load(&flags[(64 + lane) << 5],
                                           __ATOMIC_RELAXED, __HIP_MEMORY_SCOPE_AGENT);
                if (__all(f0 >= need && f1 >= need)) break;
            }
        }
        __syncthreads();

        // ---- direct load of this lane's 32 h floats from MALL into registers ----
        f32x4 h_[8];
        {
            const char* pa = (const char*)src + ((size_t)lane << 5);
            const char* pb = pa + 4096;
            asm volatile(
                "global_load_dwordx4 %0, %8, off sc0 sc1\n\t"
                "global_load_dwordx4 %1, %8, off offset:16 sc0 sc1\n\t"
                "global_load_dwordx4 %2, %8, off offset:2048 sc0 sc1\n\t"
                "global_load_dwordx4 %3, %8, off offset:2064 sc0 sc1\n\t"
                "global_load_dwordx4 %4, %9, off sc0 sc1\n\t"
                "global_load_dwordx4 %5, %9, off offset:16 sc0 sc1\n\t"
                "global_load_dwordx4 %6, %9, off offset:2048 sc0 sc1\n\t"
                "global_load_dwordx4 %7, %9, off offset:2064 sc0 sc1\n\t"
                "s_waitcnt vmcnt(0)"
                : "=&v"(h_[0]), "=&v"(h_[1]), "=&v"(h_[2]), "=&v"(h_[3]),
                  "=&v"(h_[4]), "=&v"(h_[5]), "=&v"(h_[6]), "=&v"(h_[7])
                : "v"(pa), "v"(pb)
                : "memory");
        }

        // ---- 6 rows per wave: accumulate, then pipelined butterfly reduce ----
        float pacc[6][2];
        #pragma unroll
        for (int rr6 = 0; rr6 < 6; ++rr6) {
            pacc[rr6][0] = 0.f; pacc[rr6][1] = 0.f;
            const uint4* wr4 = (const uint4*)&wlds[(w * 6 + rr6) << 10];
            #pragma unroll
            for (int c = 0; c < 2; ++c) {
                const uint4 wv = wr4[c * 64 + lane];
                const float w0 = bf_lo(wv.x), w1 = bf_hi(wv.x);
                const float w2 = bf_lo(wv.y), w3 = bf_hi(wv.y);
                const float w4 = bf_lo(wv.z), w5 = bf_hi(wv.z);
                const float w6 = bf_lo(wv.w), w7 = bf_hi(wv.w);
                {
                    const f32x4 ha = h_[c * 2], hb2 = h_[c * 2 + 1];
                    pacc[rr6][0] += w0 * ha.x + w1 * ha.y + w2 * ha.z + w3 * ha.w
                                  + w4 * hb2.x + w5 * hb2.y + w6 * hb2.z + w7 * hb2.w;
                }
                {
                    const f32x4 ha = h_[4 + c * 2], hb2 = h_[4 + c * 2 + 1];
                    pacc[rr6][1] += w0 * ha.x + w1 * ha.y + w2 * ha.z + w3 * ha.w
                                  + w4 * hb2.x + w5 * hb2.y + w6 * hb2.z + w7 * hb2.w;
                }
            }
        }
        #pragma unroll
        for (int off = 32; off > 0; off >>= 1) {
            #pragma unroll
            for (int rr6 = 0; rr6 < 6; ++rr6) {
                pacc[rr6][0] += __shfl_xor(pacc[rr6][0], off);
                pacc[rr6][1] += __shfl_xor(pacc[rr6][1], off);
            }
        }
        if (lane == 0) {
            #pragma unroll
            for (int rr6 = 0; rr6 < 6; ++rr6) {
                ghs[w * 6 + rr6][0] = pacc[rr6][0];
                ghs[w * 6 + rr6][1] = pacc[rr6][1];
            }
        }
        __syncthreads();

        // ---- pointwise update for our 8 units x 2 batches; publish to MALL ----
        if (tid < 16) {
            const float hr  = ghs[j][bb]      + bh[j];
            const float hz  = ghs[8 + j][bb]  + bh[8 + j];
            const float hnv = ghs[16 + j][bb] + bh[16 + j];
            const float rg = 1.f / (1.f + __expf(-(ir + hr)));
            const float zg = 1.f / (1.f + __expf(-(iz + hz)));
            const float ng = tanhf(inn + rg * hnv);
            const float hnew = (1.f - zg) * ng + zg * hprev;
            hprev = hnew;
            const int row = (bb << 10) | t;
            states[(size_t)row * 1024 + u0 + j] = hnew;
            __hip_atomic_store(&dst[(bb << 10) + u0 + j], hnew,
                               __ATOMIC_RELAXED, __HIP_MEMORY_SCOPE_AGENT);
        }
        if (w == 0) {
            asm volatile("s_waitcnt vmcnt(0)" ::: "memory");
            if (lane == 0)
                __hip_atomic_store(&flags[wg << 5], t + 1,
                                   __ATOMIC_RELAXED, __HIP_MEMORY_SCOPE_AGENT);
        }
        // waves 1-3 proceed; wave 0's flag store precedes its next-step poll.
    }
}

// ---------------- gate = sigmoid(states @ Wg^T + bg), one wave per row ----------------
__global__ __launch_bounds__(256) void gate_kernel(
    const float* __restrict__ states, const float* __restrict__ Wg,
    const float* __restrict__ bg, float* __restrict__ gate)
{
    const int w = threadIdx.x >> 6, lane = threadIdx.x & 63;
    const int row = blockIdx.x * 4 + w;
    const float4* sr = (const float4*)(states + (size_t)row * 1024);
    const float4* wr = (const float4*)Wg;
    float p = 0.f;
    for (int c = 0; c < 4; ++c) {
        const float4 sv = sr[c * 64 + lane];
        const float4 wv = wr[c * 64 + lane];
        p += sv.x * wv.x + sv.y * wv.y + sv.z * wv.z + sv.w * wv.w;
    }
    for (int off = 32; off > 0; off >>= 1) p += __shfl_xor(p, off);
    if (lane == 0) gate[row] = 1.f / (1.f + __expf(-(p + bg[0])));
}

// ---------------- combined = base + gate * residual ----------------
__global__ __launch_bounds__(256) void combined_kernel(
    const float* __restrict__ base, const float* __restrict__ resid,
    const float* __restrict__ gate, float* __restrict__ comb)
{
    const int idx = blockIdx.x * 256 + threadIdx.x;
    const int row = idx >> 9;
    comb[idx] = base[idx] + gate[row] * resid[idx];
}

// ---------------- attention + scatter into logits ----------------
__global__ __launch_bounds__(256) void attn_scatter(
    const float* __restrict__ q,      // [2048][256]
    const float* __restrict__ kT,     // [2][256][1024]
    const float* __restrict__ gate,   // [2048]
    const float* __restrict__ mscale, // [1]
    const int* __restrict__ ids,      // [2][1024]
    float* __restrict__ out)          // [2][1024][32000]
{
    const int i = blockIdx.x, b = blockIdx.y, t = threadIdx.x;
    if (i == 0) return;
    __shared__ float qs[256];
    __shared__ float red[256];

    qs[t] = q[((size_t)((b << 10) | i)) * 256 + t];
    __syncthreads();

    const int j0 = t * 4;
    float s[4] = {0.f, 0.f, 0.f, 0.f};
    const float* kb = kT + (size_t)b * 256 * 1024;
    if (j0 < i) {
        for (int kk = 0; kk < 256; ++kk) {
            const float qv = qs[kk];
            const float4 kv = *(const float4*)(kb + (size_t)kk * 1024 + j0);
            s[0] += qv * kv.x; s[1] += qv * kv.y; s[2] += qv * kv.z; s[3] += qv * kv.w;
        }
    }
    const float scale = 0.0625f;  // 1/sqrt(256)
    float mx = -1e30f;
    for (int e = 0; e < 4; ++e)
        if (j0 + e < i) { s[e] *= scale; mx = fmaxf(mx, s[e]); }

    red[t] = mx; __syncthreads();
    for (int o = 128; o > 0; o >>= 1) {
        if (t < o) red[t] = fmaxf(red[t], red[t + o]);
        __syncthreads();
    }
    const float m = red[0];
    __syncthreads();

    float p[4]; float ssum = 0.f;
    for (int e = 0; e < 4; ++e) {
        if (j0 + e < i) { p[e] = __expf(s[e] - m); ssum += p[e]; }
        else p[e] = 0.f;
    }
    red[t] = ssum; __syncthreads();
    for (int o = 128; o > 0; o >>= 1) {
        if (t < o) red[t] += red[t + o];
        __syncthreads();
    }
    const float denom = fmaxf(red[0], 1e-6f);
    const float g6 = gate[(b << 10) | i] * mscale[0] / denom;

    float* orow = out + ((size_t)((b << 10) | i)) * 32000;
    const int* idr = ids + (b << 10);
    for (int e = 0; e < 4; ++e)
        if (j0 + e < i) atomicAdd(&orow[idr[j0 + e]], p[e] * g6);
}

// ---------------- launch ----------------
extern "C" void kernel_launch(void* const* d_in, const int* in_sizes, int n_in,
                              void* d_out, int out_size, void* d_ws, size_t ws_size,
                              hipStream_t stream)
{
    const int*   ids     = (const int*)  d_in[0];
    const float* emb_W   = (const float*)d_in[1];
    const float* w_ih    = (const float*)d_in[2];
    const float* w_hh    = (const float*)d_in[3];
    const float* b_ih    = (const float*)d_in[4];
    const float* b_hh    = (const float*)d_in[5];
    const float* Wq      = (const float*)d_in[6];
    const float* bq      = (const float*)d_in[7];
    const float* Wk      = (const float*)d_in[8];
    const float* bk      = (const float*)d_in[9];
    const float* Wg      = (const float*)d_in[10];
    const float* bg      = (const float*)d_in[11];
    const float* W1      = (const float*)d_in[12];
    const float* b1      = (const float*)d_in[13];
    const float* W2      = (const float*)d_in[14];
    const float* b2      = (const float*)d_in[15];
    const float* Wr      = (const float*)d_in[16];
    const float* br      = (const float*)d_in[17];
    const float* mscale  = (const float*)d_in[18];
    const float* out_b   = (const float*)d_in[19];
    float* out = (float*)d_out;

    float* ws = (float*)d_ws;
    float* xp     = ws;                         // 2048*3072
    float* states = xp     + (size_t)2048 * 3072;
    float* hf     = states + (size_t)2048 * 1024;
    float* base   = hf     + (size_t)2048 * 2048;
    float* resid  = base   + (size_t)2048 * 512;
    float* qv     = resid  + (size_t)2048 * 512;
    float* kT     = qv     + (size_t)2048 * 256;
    float* comb   = kT     + (size_t)2 * 256 * 1024;
    float* gate   = comb   + (size_t)2048 * 512;
    float* hbuf   = gate   + 2048;              // 4096 floats
    int*   flags  = (int*)(hbuf + 4096);        // 128*32 padded flags

    dim3 blk(256);

    gemm_bt<ACT_NONE, true, false><<<dim3(32, 48), blk, 0, stream>>>(
        emb_W, w_ih, b_ih, xp, ids, 2048, 3072, 512);

    init_ws<<<16, blk, 0, stream>>>(hbuf, flags);
    gru_kernel<<<128, blk, 0, stream>>>(xp, w_hh, b_hh, states, hbuf, flags);

    gemm_bt<ACT_RELU2, false, false><<<dim3(32, 32), blk, 0, stream>>>(
        states, W1, b1, hf, nullptr, 2048, 2048, 1024);

    gemm_bt<ACT_NONE, false, false><<<dim3(32, 8), blk, 0, stream>>>(
        hf, W2, b2, base, nullptr, 2048, 512, 2048);

    gemm_bt<ACT_RELU, false, false><<<dim3(32, 8), blk, 0, stream>>>(
        base, Wr, br, resid, nullptr, 2048, 512, 512);

    gate_kernel<<<512, blk, 0, stream>>>(states, Wg, bg, gate);

    gemm_bt<ACT_NONE, false, false><<<dim3(32, 4), blk, 0, stream>>>(
        states, Wq, bq, qv, nullptr, 2048, 256, 1024);
    gemm_bt<ACT_NONE, false, true><<<dim3(32, 4), blk, 0, stream>>>(
        states, Wk, bk, kT, nullptr, 2048, 256, 1024);

    combined_kernel<<<4096, blk, 0, stream>>>(base, resid, gate, comb);

    gemm_bt<ACT_NONE, false, false><<<dim3(32, 500), blk, 0, stream>>>(
        comb, emb_W, out_b, out, nullptr, 2048, 32000, 512);

    attn_scatter<<<dim3(1024, 2), blk, 0, stream>>>(qv, kT, gate, mscale, ids, out);
}